// Round 3
// baseline (47.832 us; speedup 1.0000x reference)
//
#include <hip/hip_runtime.h>

#define DH 512
#define NB 2048
#define BLOCK 256
#define EPS 1e-6f

__device__ __forceinline__ float ssq8(const float4& a0, const float4& a1,
                                      const float4& b0, const float4& b1) {
    float s = 0.0f, d;
    d = a0.x - b0.x; s = fmaf(d, d, s);
    d = a0.y - b0.y; s = fmaf(d, d, s);
    d = a0.z - b0.z; s = fmaf(d, d, s);
    d = a0.w - b0.w; s = fmaf(d, d, s);
    d = a1.x - b1.x; s = fmaf(d, d, s);
    d = a1.y - b1.y; s = fmaf(d, d, s);
    d = a1.z - b1.z; s = fmaf(d, d, s);
    d = a1.w - b1.w; s = fmaf(d, d, s);
    return s;
}

// Load register stage S (8x float4) for row-pair p: rows 2p, 2p+1.
#define LOAD(S, p) do {                                                        \
    const size_t _base = (size_t)(p) * (2 * DH);                               \
    const float4* _q1 = reinterpret_cast<const float4*>(x1 + _base) + lane * 2;\
    const float4* _q2 = reinterpret_cast<const float4*>(x2 + _base) + lane * 2;\
    S[0] = _q1[0];   S[1] = _q1[1];                                            \
    S[2] = _q2[0];   S[3] = _q2[1];                                            \
    S[4] = _q1[128]; S[5] = _q1[129];                                          \
    S[6] = _q2[128]; S[7] = _q2[129];                                          \
} while (0)

// Consume stage S for row-pair p; accumulate into acc.
#define COMPUTE(S, p) do {                                                     \
    /* uniform broadcast loads covering both rows of the pair (issued early,  */\
    /* covered by the shuffle chain below)                                    */\
    const float4 _Y1 = *reinterpret_cast<const float4*>(y1  + (size_t)(p) * 4);\
    const float4 _Y2 = *reinterpret_cast<const float4*>(y2  + (size_t)(p) * 4);\
    const float4 _YP = *reinterpret_cast<const float4*>(yp1 + (size_t)(p) * 4);\
    float _s0 = ssq8(S[0], S[1], S[2], S[3]);                                  \
    float _s1 = ssq8(S[4], S[5], S[6], S[7]);                                  \
    _Pragma("unroll")                                                          \
    for (int _off = 32; _off > 0; _off >>= 1) {                                \
        _s0 += __shfl_xor(_s0, _off);                                          \
        _s1 += __shfl_xor(_s1, _off);                                          \
    }                                                                          \
    if (lane < 2) {                                                            \
        const float _ssq = lane ? _s1 : _s0;                                   \
        const float _v1x = lane ? _Y1.z : _Y1.x;                               \
        const float _v1y = lane ? _Y1.w : _Y1.y;                               \
        const float _v2x = lane ? _Y2.z : _Y2.x;                               \
        const float _v2y = lane ? _Y2.w : _Y2.y;                               \
        const float _vpx = lane ? _YP.z : _YP.x;                               \
        const float _vpy = lane ? _YP.w : _YP.y;                               \
        const float _dx = sqrtf(_ssq + EPS);                                   \
        const float _w  = (_ssq == 0.0f) ? 1.0f : _dx;  /* exact: all-eq <=> ssq==0 */\
        const float _e0 = _v1x - _v2x, _e1 = _v1y - _v2y;                      \
        const float _dy = sqrtf(fmaf(_e0, _e0, fmaf(_e1, _e1, EPS)));          \
        const float _t  = _dx - _dy;                                           \
        const float _g0 = _v1x - _vpx, _g1 = _v1y - _vpy;                      \
        acc += _t * _t / _w + _g0 * _g0 + _g1 * _g1;                           \
    }                                                                          \
} while (0)

__global__ __launch_bounds__(BLOCK) void siamese_partial(
    const float* __restrict__ x1, const float* __restrict__ x2,
    const float* __restrict__ y1, const float* __restrict__ y2,
    const float* __restrict__ yp1, float* __restrict__ partial, int B)
{
    const int lane = threadIdx.x & 63;
    const int wib  = threadIdx.x >> 6;
    const int wid  = blockIdx.x * (BLOCK >> 6) + wib;
    const int nw   = gridDim.x * (BLOCK >> 6);

    const int P     = B >> 1;        // row pairs (B is even: 65536)
    const int iters = P / nw;        // full pipelined rounds per wave (=4)
    const int rem   = P - iters * nw;

    float acc = 0.0f;

    float4 Sa[8], Sb[8];

    int i = 0;
    if (iters > 0) LOAD(Sa, wid);
    for (; i + 2 <= iters; i += 2) {
        LOAD(Sb, wid + (size_t)(i + 1) * nw);        // prefetch pair i+1
        COMPUTE(Sa, wid + (size_t)i * nw);           // consume pair i (vmcnt(8) wait)
        if (i + 2 < iters) LOAD(Sa, wid + (size_t)(i + 2) * nw);
        COMPUTE(Sb, wid + (size_t)(i + 1) * nw);
    }
    if (i < iters) {                                 // odd iters tail
        COMPUTE(Sa, wid + (size_t)i * nw);
    }
    if (wid < rem) {                                 // leftover pairs
        const int p = iters * nw + wid;
        LOAD(Sa, p);
        COMPUTE(Sa, p);
    }

    // wave-level reduce of acc (lanes 0,1 hold partials)
    #pragma unroll
    for (int off = 32; off > 0; off >>= 1)
        acc += __shfl_xor(acc, off);

    __shared__ float s[BLOCK >> 6];
    if (lane == 0) s[wib] = acc;
    __syncthreads();
    if (threadIdx.x == 0) {
        float t = 0.0f;
        #pragma unroll
        for (int i2 = 0; i2 < (BLOCK >> 6); ++i2) t += s[i2];
        partial[blockIdx.x] = t;
    }
}

__global__ __launch_bounds__(BLOCK) void siamese_final(
    const float* __restrict__ partial, float* __restrict__ out, int n)
{
    float acc = 0.0f;
    for (int i = threadIdx.x; i < n; i += BLOCK) acc += partial[i];
    #pragma unroll
    for (int off = 32; off > 0; off >>= 1)
        acc += __shfl_xor(acc, off);
    __shared__ float s[BLOCK >> 6];
    const int lane = threadIdx.x & 63;
    const int wib  = threadIdx.x >> 6;
    if (lane == 0) s[wib] = acc;
    __syncthreads();
    if (threadIdx.x == 0) {
        float t = 0.0f;
        #pragma unroll
        for (int i = 0; i < (BLOCK >> 6); ++i) t += s[i];
        out[0] = t;   // overwrite, never accumulate: safe across graph replays
    }
}

extern "C" void kernel_launch(void* const* d_in, const int* in_sizes, int n_in,
                              void* d_out, int out_size, void* d_ws, size_t ws_size,
                              hipStream_t stream) {
    const float* x1  = (const float*)d_in[0];
    const float* x2  = (const float*)d_in[1];
    const float* y1  = (const float*)d_in[2];
    const float* y2  = (const float*)d_in[3];
    const float* yp1 = (const float*)d_in[4];
    float* out = (float*)d_out;
    float* partial = (float*)d_ws;          // NB floats = 8 KB scratch

    const int B = in_sizes[0] / DH;         // 65536

    siamese_partial<<<NB, BLOCK, 0, stream>>>(x1, x2, y1, y2, yp1, partial, B);
    siamese_final<<<1, BLOCK, 0, stream>>>(partial, out, NB);
}

// Round 5
// 47.622 us; speedup vs baseline: 1.0044x; 1.0044x over previous
//
#include <hip/hip_runtime.h>

#define DH 512
#define NB 2048
#define BLOCK 256
#define EPS 1e-6f

typedef float f32x4 __attribute__((ext_vector_type(4)));

__global__ __launch_bounds__(BLOCK) void siamese_partial(
    const float* __restrict__ x1, const float* __restrict__ x2,
    const float* __restrict__ y1, const float* __restrict__ y2,
    const float* __restrict__ yp1, float* __restrict__ partial, int B)
{
    const int lane = threadIdx.x & 63;
    const int wib  = threadIdx.x >> 6;                       // wave in block
    const int wid  = blockIdx.x * (BLOCK >> 6) + wib;        // global wave id
    const int nw   = gridDim.x * (BLOCK >> 6);               // total waves

    float acc = 0.0f;

    for (int r0 = wid * 2; r0 < B; r0 += nw * 2) {
        const int r1 = r0 + 1;                               // B even
        const size_t base0 = (size_t)r0 * DH;
        const size_t base1 = (size_t)r1 * DH;
        const f32x4* pa0 = reinterpret_cast<const f32x4*>(x1 + base0) + lane * 2;
        const f32x4* pb0 = reinterpret_cast<const f32x4*>(x2 + base0) + lane * 2;
        const f32x4* pa1 = reinterpret_cast<const f32x4*>(x1 + base1) + lane * 2;
        const f32x4* pb1 = reinterpret_cast<const f32x4*>(x2 + base1) + lane * 2;

        // x1: normal (L3-cacheable — 134 MB fits in 256 MiB L3 and stays hot
        // across graph replays). x2: non-temporal (nt, no-allocate) so it
        // doesn't evict x1 — streams from HBM at full rate.
        f32x4 a00 = pa0[0], a01 = pa0[1];
        f32x4 a10 = pa1[0], a11 = pa1[1];
        f32x4 b00 = __builtin_nontemporal_load(pb0);
        f32x4 b01 = __builtin_nontemporal_load(pb0 + 1);
        f32x4 b10 = __builtin_nontemporal_load(pb1);
        f32x4 b11 = __builtin_nontemporal_load(pb1 + 1);

        float ssq0 = 0.0f, ssq1 = 0.0f;
        float d;
        d = a00.x - b00.x; ssq0 = fmaf(d, d, ssq0);
        d = a00.y - b00.y; ssq0 = fmaf(d, d, ssq0);
        d = a00.z - b00.z; ssq0 = fmaf(d, d, ssq0);
        d = a00.w - b00.w; ssq0 = fmaf(d, d, ssq0);
        d = a01.x - b01.x; ssq0 = fmaf(d, d, ssq0);
        d = a01.y - b01.y; ssq0 = fmaf(d, d, ssq0);
        d = a01.z - b01.z; ssq0 = fmaf(d, d, ssq0);
        d = a01.w - b01.w; ssq0 = fmaf(d, d, ssq0);
        d = a10.x - b10.x; ssq1 = fmaf(d, d, ssq1);
        d = a10.y - b10.y; ssq1 = fmaf(d, d, ssq1);
        d = a10.z - b10.z; ssq1 = fmaf(d, d, ssq1);
        d = a10.w - b10.w; ssq1 = fmaf(d, d, ssq1);
        d = a11.x - b11.x; ssq1 = fmaf(d, d, ssq1);
        d = a11.y - b11.y; ssq1 = fmaf(d, d, ssq1);
        d = a11.z - b11.z; ssq1 = fmaf(d, d, ssq1);
        d = a11.w - b11.w; ssq1 = fmaf(d, d, ssq1);

        // two interleaved wave-wide reductions (64 lanes)
        #pragma unroll
        for (int off = 32; off > 0; off >>= 1) {
            ssq0 += __shfl_xor(ssq0, off);
            ssq1 += __shfl_xor(ssq1, off);
        }

        // epilogue: lanes 0 and 1 handle one row each, in parallel.
        // exact-equality branch: all rows equal <=> ssq == 0 exactly.
        if (lane < 2) {
            const int   row = (lane == 0) ? r0   : r1;
            const float ssq = (lane == 0) ? ssq0 : ssq1;
            float dx = sqrtf(ssq + EPS);
            float2 v1 = *reinterpret_cast<const float2*>(y1  + (size_t)row * 2);
            float2 v2 = *reinterpret_cast<const float2*>(y2  + (size_t)row * 2);
            float2 vp = *reinterpret_cast<const float2*>(yp1 + (size_t)row * 2);
            float e0 = v1.x - v2.x, e1 = v1.y - v2.y;
            float dy = sqrtf(fmaf(e0, e0, fmaf(e1, e1, EPS)));
            float w  = (ssq == 0.0f) ? 1.0f : dx;
            float t  = dx - dy;
            float g0 = v1.x - vp.x, g1 = v1.y - vp.y;
            acc += t * t / w + g0 * g0 + g1 * g1;
        }
    }

    // once-per-wave reduction of acc (lanes 0 and 1 hold partials)
    #pragma unroll
    for (int off = 32; off > 0; off >>= 1)
        acc += __shfl_xor(acc, off);

    __shared__ float s[BLOCK >> 6];
    if (lane == 0) s[wib] = acc;
    __syncthreads();
    if (threadIdx.x == 0) {
        float t = 0.0f;
        #pragma unroll
        for (int i = 0; i < (BLOCK >> 6); ++i) t += s[i];
        partial[blockIdx.x] = t;
    }
}

__global__ __launch_bounds__(BLOCK) void siamese_final(
    const float* __restrict__ partial, float* __restrict__ out, int n)
{
    float acc = 0.0f;
    for (int i = threadIdx.x; i < n; i += BLOCK) acc += partial[i];
    #pragma unroll
    for (int off = 32; off > 0; off >>= 1)
        acc += __shfl_xor(acc, off);
    __shared__ float s[BLOCK >> 6];
    const int lane = threadIdx.x & 63;
    const int wib  = threadIdx.x >> 6;
    if (lane == 0) s[wib] = acc;
    __syncthreads();
    if (threadIdx.x == 0) {
        float t = 0.0f;
        #pragma unroll
        for (int i = 0; i < (BLOCK >> 6); ++i) t += s[i];
        out[0] = t;   // overwrite, never accumulate: safe across graph replays
    }
}

extern "C" void kernel_launch(void* const* d_in, const int* in_sizes, int n_in,
                              void* d_out, int out_size, void* d_ws, size_t ws_size,
                              hipStream_t stream) {
    const float* x1  = (const float*)d_in[0];
    const float* x2  = (const float*)d_in[1];
    const float* y1  = (const float*)d_in[2];
    const float* y2  = (const float*)d_in[3];
    const float* yp1 = (const float*)d_in[4];
    float* out = (float*)d_out;
    float* partial = (float*)d_ws;          // NB floats = 8 KB scratch

    const int B = in_sizes[0] / DH;         // 65536

    siamese_partial<<<NB, BLOCK, 0, stream>>>(x1, x2, y1, y2, yp1, partial, B);
    siamese_final<<<1, BLOCK, 0, stream>>>(partial, out, NB);
}